// Round 1
// baseline (470.373 us; speedup 1.0000x reference)
//
#include <hip/hip_runtime.h>

// Problem constants (from the reference): B=8, S=2048, N=4, D=1024.
// out[b,s,i,d] = (sum_j h_res[b,s,i,j] * x[b,s,j,d]) * h_out[b,s,d]
//             + h_post[b,s,i] * x[b,s,i,d]
//
// Pure streaming kernel: 577 MiB total traffic, ~92 us floor at 6.3 TB/s.

#define NB 8
#define NS 2048
#define NN 4
#define ND 1024

__global__ __launch_bounds__(256) void fused_stream_mix(
    const float* __restrict__ x,      // [B*S, N, D]
    const float* __restrict__ h_res,  // [B*S, N, N]
    const float* __restrict__ h_out,  // [B*S, D]
    const float* __restrict__ h_post, // [B*S, N]
    float* __restrict__ out)          // [B*S, N, D]
{
    const int bs = blockIdx.x;        // 0 .. B*S-1
    const int t  = threadIdx.x;       // 0 .. 255 ; owns d = 4t .. 4t+3

    __shared__ float s_res[NN * NN];  // 16 mixing coefficients
    __shared__ float s_post[NN];      // 4 residual scales

    if (t < NN * NN) s_res[t]  = h_res[(size_t)bs * (NN * NN) + t];
    if (t < NN)      s_post[t] = h_post[(size_t)bs * NN + t];
    __syncthreads();

    const float4* xp = (const float4*)(x + (size_t)bs * NN * ND);
    const float4  x0 = xp[0 * (ND / 4) + t];
    const float4  x1 = xp[1 * (ND / 4) + t];
    const float4  x2 = xp[2 * (ND / 4) + t];
    const float4  x3 = xp[3 * (ND / 4) + t];
    const float4  ho = ((const float4*)(h_out + (size_t)bs * ND))[t];

    float4* op = (float4*)(out + (size_t)bs * NN * ND);

    #pragma unroll
    for (int i = 0; i < NN; ++i) {
        const float r0 = s_res[i * NN + 0];
        const float r1 = s_res[i * NN + 1];
        const float r2 = s_res[i * NN + 2];
        const float r3 = s_res[i * NN + 3];
        const float hp = s_post[i];
        const float4 xi = (i == 0) ? x0 : (i == 1) ? x1 : (i == 2) ? x2 : x3;

        float4 m;
        m.x = (r0 * x0.x + r1 * x1.x + r2 * x2.x + r3 * x3.x) * ho.x + hp * xi.x;
        m.y = (r0 * x0.y + r1 * x1.y + r2 * x2.y + r3 * x3.y) * ho.y + hp * xi.y;
        m.z = (r0 * x0.z + r1 * x1.z + r2 * x2.z + r3 * x3.z) * ho.z + hp * xi.z;
        m.w = (r0 * x0.w + r1 * x1.w + r2 * x2.w + r3 * x3.w) * ho.w + hp * xi.w;

        op[i * (ND / 4) + t] = m;
    }
}

extern "C" void kernel_launch(void* const* d_in, const int* in_sizes, int n_in,
                              void* d_out, int out_size, void* d_ws, size_t ws_size,
                              hipStream_t stream) {
    const float* x      = (const float*)d_in[0];
    const float* h_res  = (const float*)d_in[1];
    const float* h_out  = (const float*)d_in[2];
    const float* h_post = (const float*)d_in[3];
    float* out = (float*)d_out;

    // One block per (b,s) position; 256 threads cover D=1024 as float4.
    fused_stream_mix<<<NB * NS, 256, 0, stream>>>(x, h_res, h_out, h_post, out);
}